// Round 2
// baseline (535.057 us; speedup 1.0000x reference)
//
#include <hip/hip_runtime.h>
#include <stdint.h>

typedef unsigned short u16;
typedef unsigned int   u32;

#define NB   16
#define SQL  2048
#define SKVL 2048
#define DHD  256
#define BQ   64
#define BKV  32
#define NITER (SKVL / BKV)    // 64
#define KSS  264              // Ks row stride (u16): 256 + 8 pad, rows 16B-aligned
#define VTS  20               // Vt row stride (u32): 16 kv-pairs + 4 pad, rows 16B-aligned
#define PSS  40               // Ps row stride (u16)
#define SCALE 0.022097086912079612f   // 1/sqrt(2048)

typedef __bf16 bf16x8 __attribute__((ext_vector_type(8)));
typedef float  f32x4  __attribute__((ext_vector_type(4)));

__device__ __forceinline__ u16 f2b(float f) {           // fp32 -> bf16 RNE
    union { float f; u32 i; } v; v.f = f;
    u32 x = v.i;
    return (u16)((x + 0x7fffu + ((x >> 16) & 1u)) >> 16);
}

__global__ __launch_bounds__(256, 2)
void fa_kernel(const float* __restrict__ x, const float* __restrict__ y,
               const float* __restrict__ mask, float* __restrict__ out)
{
    // LDS: 16896 + 20480 + 5120 = 42496 B  -> 2 blocks/CU
    __shared__ __align__(16) u16 Ks[BKV * KSS];   // K tile bf16, row-major (kv, d)
    __shared__ __align__(16) u32 Vt[DHD * VTS];   // V^T tile: row d, packed kv pairs
    __shared__ __align__(16) u16 Ps[BQ * PSS];    // P tile bf16 (q, kv)

    const int tid  = threadIdx.x;
    const int wv   = tid >> 6;
    const int lane = tid & 63;
    const int l16  = lane & 15;
    const int quad = lane >> 4;

    const int b  = blockIdx.x >> 5;
    const int q0 = (blockIdx.x & 31) * BQ;

    // ---- Q fragments: A[m=l16][k=quad*8+j], converted fp32 -> bf16 ----
    bf16x8 qfrag[8];
    {
        const float* xq = x + ((size_t)(b * SQL + q0 + wv * 16 + l16)) * DHD + quad * 8;
        #pragma unroll
        for (int s = 0; s < 8; ++s) {
            const float4 a = *(const float4*)(xq + s * 32);
            const float4 c = *(const float4*)(xq + s * 32 + 4);
            union { u32 w[4]; bf16x8 v; } u;
            u.w[0] = (u32)f2b(a.x) | ((u32)f2b(a.y) << 16);
            u.w[1] = (u32)f2b(a.z) | ((u32)f2b(a.w) << 16);
            u.w[2] = (u32)f2b(c.x) | ((u32)f2b(c.y) << 16);
            u.w[3] = (u32)f2b(c.z) | ((u32)f2b(c.w) << 16);
            qfrag[s] = u.v;
        }
    }

    f32x4 o[16] = {};
    float lsum[4] = {0.f, 0.f, 0.f, 0.f};

    // staging: thread owns kv rows {2*kv2, 2*kv2+1}, d cols [dc*16, dc*16+16)
    const int kv2 = tid & 15;
    const int dc  = tid >> 4;
    const float* ybase = y + ((size_t)b * SKVL) * DHD;

    float4 r0[4], r1[4];
    {
        const float* p0 = ybase + (size_t)(2 * kv2) * DHD + dc * 16;
        const float* p1 = p0 + DHD;
        #pragma unroll
        for (int p = 0; p < 4; ++p) { r0[p] = *(const float4*)(p0 + p * 4);
                                      r1[p] = *(const float4*)(p1 + p * 4); }
    }

    const float* mbase = mask + ((size_t)(b * SQL + q0 + wv * 16 + quad * 4)) * SKVL;

    for (int it = 0; it < NITER; ++it) {
        const int kv0 = it * BKV;

        __syncthreads();   // previous iter's Ks/Vt readers done
        {   // convert fp32 -> bf16 and stage both layouts
            u16 e0[16], e1[16];
            #pragma unroll
            for (int p = 0; p < 4; ++p) {
                e0[p*4+0]=f2b(r0[p].x); e0[p*4+1]=f2b(r0[p].y);
                e0[p*4+2]=f2b(r0[p].z); e0[p*4+3]=f2b(r0[p].w);
                e1[p*4+0]=f2b(r1[p].x); e1[p*4+1]=f2b(r1[p].y);
                e1[p*4+2]=f2b(r1[p].z); e1[p*4+3]=f2b(r1[p].w);
            }
            union { u32 w[4]; uint4 q; } k0a, k0b, k1a, k1b;
            #pragma unroll
            for (int i = 0; i < 4; ++i) {
                k0a.w[i] = (u32)e0[2*i]     | ((u32)e0[2*i+1]   << 16);
                k0b.w[i] = (u32)e0[8+2*i]   | ((u32)e0[8+2*i+1] << 16);
                k1a.w[i] = (u32)e1[2*i]     | ((u32)e1[2*i+1]   << 16);
                k1b.w[i] = (u32)e1[8+2*i]   | ((u32)e1[8+2*i+1] << 16);
            }
            *(uint4*)(&Ks[(2*kv2)  *KSS + dc*16])     = k0a.q;
            *(uint4*)(&Ks[(2*kv2)  *KSS + dc*16 + 8]) = k0b.q;
            *(uint4*)(&Ks[(2*kv2+1)*KSS + dc*16])     = k1a.q;
            *(uint4*)(&Ks[(2*kv2+1)*KSS + dc*16 + 8]) = k1b.q;
            #pragma unroll
            for (int e = 0; e < 16; ++e)
                Vt[(dc*16 + e)*VTS + kv2] = (u32)e0[e] | ((u32)e1[e] << 16);
        }
        __syncthreads();

        // prefetch next y tile (in flight across this iter's compute)
        if (it + 1 < NITER) {
            const float* p0 = ybase + (size_t)(kv0 + BKV + 2 * kv2) * DHD + dc * 16;
            const float* p1 = p0 + DHD;
            #pragma unroll
            for (int p = 0; p < 4; ++p) { r0[p] = *(const float4*)(p0 + p * 4);
                                          r1[p] = *(const float4*)(p1 + p * 4); }
        }

        // mask loads (fp32, C-layout positions)
        float mk0[4], mk1[4];
        #pragma unroll
        for (int r = 0; r < 4; ++r) {
            const float* mp = mbase + (size_t)r * SKVL + kv0;
            mk0[r] = mp[l16];
            mk1[r] = mp[16 + l16];
        }

        // ---- S = Q K^T : two 16-col tiles, K=256 in 8 MFMA steps each ----
        f32x4 acc0 = {}, acc1 = {};
        #pragma unroll
        for (int s = 0; s < 8; ++s) {
            bf16x8 b0 = *(const bf16x8*)(&Ks[ l16      * KSS + s*32 + quad*8]);
            bf16x8 b1 = *(const bf16x8*)(&Ks[(16+l16)  * KSS + s*32 + quad*8]);
            acc0 = __builtin_amdgcn_mfma_f32_16x16x32_bf16(qfrag[s], b0, acc0, 0, 0, 0);
            acc1 = __builtin_amdgcn_mfma_f32_16x16x32_bf16(qfrag[s], b1, acc1, 0, 0, 0);
        }

        // ---- p = exp(s * mask * scale); no max-subtraction (|arg| <= ~7) ----
        #pragma unroll
        for (int r = 0; r < 4; ++r) {
            float p0 = __expf(acc0[r] * mk0[r] * SCALE);
            float p1 = __expf(acc1[r] * mk1[r] * SCALE);
            lsum[r] += p0 + p1;
            u16* pr = &Ps[(wv*16 + quad*4 + r) * PSS];
            pr[l16]      = f2b(p0);
            pr[16 + l16] = f2b(p1);
        }
        // Ps rows are wave-private (written and read by the same wave):
        // in-wave lgkmcnt ordering suffices, no barrier needed here.

        // ---- O += P V ----
        bf16x8 afrag = *(const bf16x8*)(&Ps[(wv*16 + l16) * PSS + quad*8]);
        #pragma unroll
        for (int t = 0; t < 16; ++t) {
            bf16x8 bfrag = *(const bf16x8*)(&Vt[(t*16 + l16) * VTS + quad*4]);
            o[t] = __builtin_amdgcn_mfma_f32_16x16x32_bf16(afrag, bfrag, o[t], 0, 0, 0);
        }
    }

    // ---- row-sum reduce across the 16 lanes holding each row ----
    #pragma unroll
    for (int r = 0; r < 4; ++r) {
        float v = lsum[r];
        v += __shfl_xor(v, 1);
        v += __shfl_xor(v, 2);
        v += __shfl_xor(v, 4);
        v += __shfl_xor(v, 8);
        lsum[r] = 1.0f / v;
    }

    // ---- epilogue: out = O / l + x  (fp32) ----
    const int qrow = q0 + wv * 16 + quad * 4;
    #pragma unroll
    for (int r = 0; r < 4; ++r) {
        const size_t rowoff = ((size_t)(b * SQL + qrow + r)) * DHD;
        #pragma unroll
        for (int t = 0; t < 16; ++t) {
            const int d = t * 16 + l16;
            out[rowoff + d] = o[t][r] * lsum[r] + x[rowoff + d];
        }
    }
}

extern "C" void kernel_launch(void* const* d_in, const int* in_sizes, int n_in,
                              void* d_out, int out_size, void* d_ws, size_t ws_size,
                              hipStream_t stream) {
    const float* x    = (const float*)d_in[0];
    const float* y    = (const float*)d_in[1];
    const float* mask = (const float*)d_in[2];
    float* out        = (float*)d_out;
    dim3 grid(NB * (SQL / BQ));   // 512 blocks = 2 per CU
    fa_kernel<<<grid, 256, 0, stream>>>(x, y, mask, out);
}

// Round 3
// 501.679 us; speedup vs baseline: 1.0665x; 1.0665x over previous
//
#include <hip/hip_runtime.h>
#include <stdint.h>

typedef unsigned short u16;
typedef unsigned int   u32;

#define NB   16
#define SQL  2048
#define SKVL 2048
#define DHD  256
#define BQ   64
#define BKV  32
#define NITER (SKVL / BKV)    // 64
#define KSS  264              // Ks row stride (u16): 256 + 8 pad, rows 16B-aligned
#define VTG  328              // Vt u32 stride per 16-d-row group (16*20 + 8 pad)
#define PSS  40               // Ps row stride (u16)
#define SCALE 0.022097086912079612f   // 1/sqrt(2048)

typedef __bf16 bf16x8 __attribute__((ext_vector_type(8)));
typedef float  f32x4  __attribute__((ext_vector_type(4)));

__device__ __forceinline__ u16 f2b(float f) {           // fp32 -> bf16 RNE
    union { float f; u32 i; } v; v.f = f;
    u32 x = v.i;
    return (u16)((x + 0x7fffu + ((x >> 16) & 1u)) >> 16);
}

__global__ __launch_bounds__(256, 2)
void fa_kernel(const float* __restrict__ x, const float* __restrict__ y,
               const float* __restrict__ mask, float* __restrict__ out)
{
    // LDS: 16896 + 20992 + 5120 = 43008 B  -> 2 blocks/CU (grid-limited anyway)
    __shared__ __align__(16) u16 Ks[BKV * KSS];   // K tile bf16, row-major (kv, d)
    __shared__ __align__(16) u32 Vt[16 * VTG];    // V^T: group g (d=g*16+e), packed kv pairs
    __shared__ __align__(16) u16 Ps[BQ * PSS];    // P tile bf16 (q, kv)

    const int tid  = threadIdx.x;
    const int wv   = tid >> 6;
    const int lane = tid & 63;
    const int l16  = lane & 15;
    const int quad = lane >> 4;

    const int b  = blockIdx.x >> 5;
    const int q0 = (blockIdx.x & 31) * BQ;

    // ---- Q fragments: A[m=l16][k=quad*8+j], converted fp32 -> bf16 ----
    bf16x8 qfrag[8];
    {
        const float* xq = x + ((size_t)(b * SQL + q0 + wv * 16 + l16)) * DHD + quad * 8;
        #pragma unroll
        for (int s = 0; s < 8; ++s) {
            const float4 a = *(const float4*)(xq + s * 32);
            const float4 c = *(const float4*)(xq + s * 32 + 4);
            union { u32 w[4]; bf16x8 v; } u;
            u.w[0] = (u32)f2b(a.x) | ((u32)f2b(a.y) << 16);
            u.w[1] = (u32)f2b(a.z) | ((u32)f2b(a.w) << 16);
            u.w[2] = (u32)f2b(c.x) | ((u32)f2b(c.y) << 16);
            u.w[3] = (u32)f2b(c.z) | ((u32)f2b(c.w) << 16);
            qfrag[s] = u.v;
        }
    }

    f32x4 o[16] = {};
    float lsum[4] = {0.f, 0.f, 0.f, 0.f};

    // staging: thread owns kv rows {2*kv2, 2*kv2+1}, d cols [dc*16, dc*16+16)
    const int kv2 = tid & 15;
    const int dc  = tid >> 4;
    const float* ybase = y + ((size_t)b * SKVL) * DHD;

    float4 r0[4], r1[4];
    {
        const float* p0 = ybase + (size_t)(2 * kv2) * DHD + dc * 16;
        const float* p1 = p0 + DHD;
        #pragma unroll
        for (int p = 0; p < 4; ++p) { r0[p] = *(const float4*)(p0 + p * 4);
                                      r1[p] = *(const float4*)(p1 + p * 4); }
    }

    const float* mbase = mask + ((size_t)(b * SQL + q0 + wv * 16 + quad * 4)) * SKVL;

    // ---- mask double-buffer: preload tile 0 ----
    float mkc0[4], mkc1[4], mkn0[4], mkn1[4];
    #pragma unroll
    for (int r = 0; r < 4; ++r) {
        const float* mp = mbase + (size_t)r * SKVL;
        mkc0[r] = mp[l16];
        mkc1[r] = mp[16 + l16];
    }

    for (int it = 0; it < NITER; ++it) {
        const int kv0 = it * BKV;

        __syncthreads();   // previous iter's Ks/Vt readers done
        {   // convert fp32 -> bf16 and stage both layouts
            u16 e0[16], e1[16];
            #pragma unroll
            for (int p = 0; p < 4; ++p) {
                e0[p*4+0]=f2b(r0[p].x); e0[p*4+1]=f2b(r0[p].y);
                e0[p*4+2]=f2b(r0[p].z); e0[p*4+3]=f2b(r0[p].w);
                e1[p*4+0]=f2b(r1[p].x); e1[p*4+1]=f2b(r1[p].y);
                e1[p*4+2]=f2b(r1[p].z); e1[p*4+3]=f2b(r1[p].w);
            }
            union { u32 w[4]; uint4 q; } k0a, k0b, k1a, k1b;
            #pragma unroll
            for (int i = 0; i < 4; ++i) {
                k0a.w[i] = (u32)e0[2*i]     | ((u32)e0[2*i+1]   << 16);
                k0b.w[i] = (u32)e0[8+2*i]   | ((u32)e0[8+2*i+1] << 16);
                k1a.w[i] = (u32)e1[2*i]     | ((u32)e1[2*i+1]   << 16);
                k1b.w[i] = (u32)e1[8+2*i]   | ((u32)e1[8+2*i+1] << 16);
            }
            *(uint4*)(&Ks[(2*kv2)  *KSS + dc*16])     = k0a.q;
            *(uint4*)(&Ks[(2*kv2)  *KSS + dc*16 + 8]) = k0b.q;
            *(uint4*)(&Ks[(2*kv2+1)*KSS + dc*16])     = k1a.q;
            *(uint4*)(&Ks[(2*kv2+1)*KSS + dc*16 + 8]) = k1b.q;
            // grouped layout: banks (dc*8 + kv2) % 32 -> 2 lanes/bank = conflict-free
            #pragma unroll
            for (int e = 0; e < 16; ++e)
                Vt[dc*VTG + e*20 + kv2] = (u32)e0[e] | ((u32)e1[e] << 16);
        }
        __syncthreads();

        // prefetch next y tile (in flight across this iter's compute)
        if (it + 1 < NITER) {
            const float* p0 = ybase + (size_t)(kv0 + BKV + 2 * kv2) * DHD + dc * 16;
            const float* p1 = p0 + DHD;
            #pragma unroll
            for (int p = 0; p < 4; ++p) { r0[p] = *(const float4*)(p0 + p * 4);
                                          r1[p] = *(const float4*)(p1 + p * 4); }
        }

        // prefetch NEXT iter's mask (consumed next iter -> full-iter latency cover)
        {
            const int kvn = (it + 1 < NITER) ? (kv0 + BKV) : 0;
            #pragma unroll
            for (int r = 0; r < 4; ++r) {
                const float* mp = mbase + (size_t)r * SKVL + kvn;
                mkn0[r] = mp[l16];
                mkn1[r] = mp[16 + l16];
            }
        }

        // ---- S = Q K^T : two 16-col tiles, K=256 in 8 MFMA steps each ----
        f32x4 acc0 = {}, acc1 = {};
        #pragma unroll
        for (int s = 0; s < 8; ++s) {
            bf16x8 b0 = *(const bf16x8*)(&Ks[ l16      * KSS + s*32 + quad*8]);
            bf16x8 b1 = *(const bf16x8*)(&Ks[(16+l16)  * KSS + s*32 + quad*8]);
            acc0 = __builtin_amdgcn_mfma_f32_16x16x32_bf16(qfrag[s], b0, acc0, 0, 0, 0);
            acc1 = __builtin_amdgcn_mfma_f32_16x16x32_bf16(qfrag[s], b1, acc1, 0, 0, 0);
        }

        // ---- p = exp(s * mask * scale); no max-subtraction (|arg| <= ~7) ----
        #pragma unroll
        for (int r = 0; r < 4; ++r) {
            float p0 = __expf(acc0[r] * mkc0[r] * SCALE);
            float p1 = __expf(acc1[r] * mkc1[r] * SCALE);
            lsum[r] += p0 + p1;
            u16* pr = &Ps[(wv*16 + quad*4 + r) * PSS];
            pr[l16]      = f2b(p0);
            pr[16 + l16] = f2b(p1);
        }
        // Ps rows are wave-private: in-wave lgkmcnt ordering suffices, no barrier.

        // ---- O += P V ----
        bf16x8 afrag = *(const bf16x8*)(&Ps[(wv*16 + l16) * PSS + quad*8]);
        #pragma unroll
        for (int t = 0; t < 16; ++t) {
            bf16x8 bfrag = *(const bf16x8*)(&Vt[t*VTG + l16*20 + quad*4]);
            o[t] = __builtin_amdgcn_mfma_f32_16x16x32_bf16(afrag, bfrag, o[t], 0, 0, 0);
        }

        // rotate mask double-buffer
        #pragma unroll
        for (int r = 0; r < 4; ++r) { mkc0[r] = mkn0[r]; mkc1[r] = mkn1[r]; }
    }

    // ---- row-sum reduce across the 16 lanes holding each row ----
    #pragma unroll
    for (int r = 0; r < 4; ++r) {
        float v = lsum[r];
        v += __shfl_xor(v, 1);
        v += __shfl_xor(v, 2);
        v += __shfl_xor(v, 4);
        v += __shfl_xor(v, 8);
        lsum[r] = 1.0f / v;
    }

    // ---- epilogue: out = O / l + x  (fp32) ----
    const int qrow = q0 + wv * 16 + quad * 4;
    #pragma unroll
    for (int r = 0; r < 4; ++r) {
        const size_t rowoff = ((size_t)(b * SQL + qrow + r)) * DHD;
        #pragma unroll
        for (int t = 0; t < 16; ++t) {
            const int d = t * 16 + l16;
            out[rowoff + d] = o[t][r] * lsum[r] + x[rowoff + d];
        }
    }
}

extern "C" void kernel_launch(void* const* d_in, const int* in_sizes, int n_in,
                              void* d_out, int out_size, void* d_ws, size_t ws_size,
                              hipStream_t stream) {
    const float* x    = (const float*)d_in[0];
    const float* y    = (const float*)d_in[1];
    const float* mask = (const float*)d_in[2];
    float* out        = (float*)d_out;
    dim3 grid(NB * (SQL / BQ));   // 512 blocks = 2 per CU
    fa_kernel<<<grid, 256, 0, stream>>>(x, y, mask, out);
}

// Round 4
// 472.684 us; speedup vs baseline: 1.1320x; 1.0613x over previous
//
#include <hip/hip_runtime.h>
#include <stdint.h>

typedef unsigned short u16;
typedef unsigned int   u32;

#define NB   16
#define SQL  2048
#define SKVL 2048
#define DHD  256
#define SCALE 0.022097086912079612f   // 1/sqrt(2048)

typedef __bf16 bf16x8 __attribute__((ext_vector_type(8)));
typedef float  f32x4  __attribute__((ext_vector_type(4)));
typedef float  f32x16 __attribute__((ext_vector_type(16)));

__device__ __forceinline__ u16 f2b(float f) {           // fp32 -> bf16 RNE
    union { float f; u32 i; } v; v.f = f;
    u32 x = v.i;
    return (u16)((x + 0x7fffu + ((x >> 16) & 1u)) >> 16);
}

__device__ __forceinline__ void async_cp16(const void* g, void* l) {
    __builtin_amdgcn_global_load_lds(
        (const __attribute__((address_space(1))) u32*)g,
        (__attribute__((address_space(3))) u32*)l, 16, 0, 0);
}

// ---------------------------------------------------------------------------
// Prepass: y (fp32) -> yb (bf16 kv-major, chunk c stored at c^(kv&7), 512B rows)
//                   -> ybT (bf16 tiled [b][kvblk64][d:256][chunk c at c^(d&7)], 128B rows)
// grid 1024 x 256
// ---------------------------------------------------------------------------
__global__ __launch_bounds__(256)
void prepass(const float* __restrict__ y, u16* __restrict__ ws)
{
    u16* yb  = ws;                    // 8,388,608 u16
    u16* ybT = ws + 8388608;

    const int tid = threadIdx.x;
    if (blockIdx.x < 512) {
        // ---- yb: kv-major swizzled ----
        const int b   = blockIdx.x >> 5;
        const int seg = blockIdx.x & 31;          // 64 kv rows
        const int r   = tid >> 2;                 // 0..63 local kv
        const int dq  = tid & 3;                  // 64-d quarter
        const int kvg = seg * 64 + r;
        const float* src = y + ((size_t)(b * SKVL + kvg)) * DHD + dq * 64;
        u16* dst = yb + ((size_t)(b * SKVL + kvg)) * DHD;
        #pragma unroll
        for (int j = 0; j < 8; ++j) {             // 8 chunks of 8 floats
            const float4 a = *(const float4*)(src + j * 8);
            const float4 c4 = *(const float4*)(src + j * 8 + 4);
            union { u32 w[4]; uint4 q; } u;
            u.w[0] = (u32)f2b(a.x)  | ((u32)f2b(a.y)  << 16);
            u.w[1] = (u32)f2b(a.z)  | ((u32)f2b(a.w)  << 16);
            u.w[2] = (u32)f2b(c4.x) | ((u32)f2b(c4.y) << 16);
            u.w[3] = (u32)f2b(c4.z) | ((u32)f2b(c4.w) << 16);
            const int pos = (dq * 8 + j) ^ (kvg & 7);
            *(uint4*)(dst + pos * 8) = u.q;
        }
    } else {
        // ---- ybT: per-64kv tile, d-major swizzled ----
        const int j     = blockIdx.x - 512;
        const int b     = j >> 5;
        const int kvblk = j & 31;                 // kv [kvblk*64, +64)
        const int d     = tid;                    // 0..255
        const int kv0   = kvblk * 64;
        u16* dst = ybT + ((size_t)(b * 32 + kvblk)) * 16384 + d * 64;
        #pragma unroll
        for (int c = 0; c < 8; ++c) {             // chunk = 8 consecutive kv
            float v[8];
            #pragma unroll
            for (int e = 0; e < 8; ++e)
                v[e] = y[((size_t)(b * SKVL + kv0 + 8 * c + e)) * DHD + d];
            union { u32 w[4]; uint4 q; } u;
            #pragma unroll
            for (int i = 0; i < 4; ++i)
                u.w[i] = (u32)f2b(v[2 * i]) | ((u32)f2b(v[2 * i + 1]) << 16);
            const int p = c ^ (d & 7);
            *(uint4*)(dst + p * 8) = u.q;
        }
    }
}

// ---------------------------------------------------------------------------
// Main flash kernel: BQ=64, BKV=64, 32x32x16 MFMA, DMA-staged swizzled tiles
// grid 512 x 256, 2 blocks/CU (LDS 75,264 B)
// ---------------------------------------------------------------------------
__global__ __launch_bounds__(256, 2)
void fa_main(const float* __restrict__ x, const float* __restrict__ mask,
             const u16* __restrict__ ws, float* __restrict__ out)
{
    __shared__ __align__(16) u16 Ks[16384];      // 64 kv x 256 d bf16, swizzled
    __shared__ __align__(16) u16 Vt[16384];      // 256 d x 64 kv bf16, swizzled
    __shared__ __align__(16) u16 Ps[64 * 72];    // P tile (q, kv), +8 pad
    __shared__ float Lred[2][64];                // row-sum partials per kh

    const u16* yb  = ws;
    const u16* ybT = ws + 8388608;

    const int tid  = threadIdx.x;
    const int wv   = tid >> 6;
    const int lane = tid & 63;
    const int n    = lane & 31;
    const int hi   = lane >> 5;
    const int qh   = wv & 1;                     // q half
    const int kh   = wv >> 1;                    // kv half

    const int b  = blockIdx.x >> 5;
    const int q0 = (blockIdx.x & 31) * 64;

    // ---- Q A-frags: A[m=lane&31][k=16s+8hi+j], fp32 -> bf16 ----
    bf16x8 qfrag[16];
    {
        const float* xq = x + ((size_t)(b * SQL + q0 + 32 * qh + n)) * DHD + 8 * hi;
        #pragma unroll
        for (int s = 0; s < 16; ++s) {
            const float4 a  = *(const float4*)(xq + s * 16);
            const float4 c4 = *(const float4*)(xq + s * 16 + 4);
            union { u32 w[4]; bf16x8 v; } u;
            u.w[0] = (u32)f2b(a.x)  | ((u32)f2b(a.y)  << 16);
            u.w[1] = (u32)f2b(a.z)  | ((u32)f2b(a.w)  << 16);
            u.w[2] = (u32)f2b(c4.x) | ((u32)f2b(c4.y) << 16);
            u.w[3] = (u32)f2b(c4.z) | ((u32)f2b(c4.w) << 16);
            qfrag[s] = u.v;
        }
    }

    f32x16 o0 = {}, o1 = {}, o2 = {}, o3 = {};
    float lsum[16];
    #pragma unroll
    for (int r = 0; r < 16; ++r) lsum[r] = 0.f;

    // mask base: lane covers (q-row per reg r, kv = it*64 + 32kh + n)
    const float* mrow = mask + ((size_t)(b * SQL + q0 + 32 * qh + 4 * hi)) * SKVL
                             + 32 * kh + n;
    // per-reg row offset (row = (r&3) + 8*(r>>2) + 4*hi, the 4*hi is folded in mrow)
    #define ROFF(r) ((size_t)(((r) & 3) + 8 * ((r) >> 2)) * SKVL)

    float mkc[16], mkn[16];
    #pragma unroll
    for (int r = 0; r < 16; ++r) mkc[r] = mrow[ROFF(r)];

    // ---- DMA tile 0 ----
    {
        const char* gk = (const char*)(yb + ((size_t)b * SKVL) * DHD) + wv * 8192 + lane * 16;
        const char* gv = (const char*)(ybT + ((size_t)b * 32) * 16384) + wv * 8192 + lane * 16;
        char* lk = ((char*)Ks) + wv * 8192;
        char* lv = ((char*)Vt) + wv * 8192;
        #pragma unroll
        for (int i = 0; i < 8; ++i) { async_cp16(gk + i * 1024, lk + i * 1024);
                                      async_cp16(gv + i * 1024, lv + i * 1024); }
    }
    __syncthreads();   // drain tile-0 DMA

    for (int it = 0; it < 32; ++it) {
        // prefetch next mask tile (in flight across the whole iteration)
        const size_t kvn = (it + 1 < 32) ? (size_t)(it + 1) * 64 : 0;
        #pragma unroll
        for (int r = 0; r < 16; ++r) mkn[r] = mrow[ROFF(r) + kvn];

        // ---- S = Q K^T : one 32x32 subtile per wave, K=256 in 16 MFMA ----
        f32x16 sacc = {};
        const int kvloc = 32 * kh + n;
        #pragma unroll
        for (int s = 0; s < 16; ++s) {
            const int p = (2 * s + hi) ^ (kvloc & 7);
            bf16x8 bf = *(const bf16x8*)(&Ks[kvloc * 256 + p * 8]);
            sacc = __builtin_amdgcn_mfma_f32_32x32x16_bf16(qfrag[s], bf, sacc, 0, 0, 0);
        }

        // ---- p = exp(s*mask*scale), accumulate row sums, write Ps ----
        #pragma unroll
        for (int r = 0; r < 16; ++r) {
            const int rowloc = (r & 3) + 8 * (r >> 2) + 4 * hi;
            float pv = __expf(sacc[r] * mkc[r] * SCALE);
            lsum[r] += pv;
            Ps[(32 * qh + rowloc) * 72 + 32 * kh + n] = f2b(pv);
        }

        __syncthreads();   // C: Ps complete (cross-wave), all QK reads done

        // Ks DMA for next tile — hidden under PV
        if (it + 1 < 32) {
            const char* gk = (const char*)(yb + ((size_t)(b * SKVL + (it + 1) * 64)) * DHD)
                             + wv * 8192 + lane * 16;
            char* lk = ((char*)Ks) + wv * 8192;
            #pragma unroll
            for (int i = 0; i < 8; ++i) async_cp16(gk + i * 1024, lk + i * 1024);
        }

        // ---- O += P V : wave covers q[32qh,+32) x d[128kh,+128) ----
        bf16x8 pa[4];
        #pragma unroll
        for (int s = 0; s < 4; ++s)
            pa[s] = *(const bf16x8*)(&Ps[(32 * qh + n) * 72 + 16 * s + 8 * hi]);
        #pragma unroll
        for (int t = 0; t < 4; ++t) {
            const int d = 128 * kh + 32 * t + n;
            f32x16 acc = (t == 0) ? o0 : (t == 1) ? o1 : (t == 2) ? o2 : o3;
            #pragma unroll
            for (int s = 0; s < 4; ++s) {
                const int p = (2 * s + hi) ^ (d & 7);
                bf16x8 bf = *(const bf16x8*)(&Vt[d * 64 + p * 8]);
                acc = __builtin_amdgcn_mfma_f32_32x32x16_bf16(pa[s], bf, acc, 0, 0, 0);
            }
            if (t == 0) o0 = acc; else if (t == 1) o1 = acc; else if (t == 2) o2 = acc; else o3 = acc;
        }

        __syncthreads();   // A: PV done reading Vt/Ps

        // Vt DMA for next tile
        if (it + 1 < 32) {
            const char* gv = (const char*)(ybT + ((size_t)(b * 32 + it + 1)) * 16384)
                             + wv * 8192 + lane * 16;
            char* lv = ((char*)Vt) + wv * 8192;
            #pragma unroll
            for (int i = 0; i < 8; ++i) async_cp16(gv + i * 1024, lv + i * 1024);
        }
        __syncthreads();   // B: drain DMA before next QK

        #pragma unroll
        for (int r = 0; r < 16; ++r) mkc[r] = mkn[r];
    }

    // ---- row-sum reduction: over 32 lanes sharing each row, then across kh ----
    #pragma unroll
    for (int r = 0; r < 16; ++r) {
        float v = lsum[r];
        v += __shfl_xor(v, 1);
        v += __shfl_xor(v, 2);
        v += __shfl_xor(v, 4);
        v += __shfl_xor(v, 8);
        v += __shfl_xor(v, 16);
        if (n == 0) {
            const int rowloc = (r & 3) + 8 * (r >> 2) + 4 * hi;
            Lred[kh][32 * qh + rowloc] = v;
        }
    }
    __syncthreads();

    float inv[16];
    #pragma unroll
    for (int r = 0; r < 16; ++r) {
        const int qloc = 32 * qh + (r & 3) + 8 * (r >> 2) + 4 * hi;
        inv[r] = 1.0f / (Lred[0][qloc] + Lred[1][qloc]);
    }

    // ---- epilogue: out = O/l + x ----
    #pragma unroll
    for (int r = 0; r < 16; ++r) {
        const int qloc = 32 * qh + (r & 3) + 8 * (r >> 2) + 4 * hi;
        const size_t rowoff = ((size_t)(b * SQL + q0 + qloc)) * DHD;
        #pragma unroll
        for (int t = 0; t < 4; ++t) {
            const int d = 128 * kh + 32 * t + n;
            const float ov = (t == 0) ? o0[r] : (t == 1) ? o1[r] : (t == 2) ? o2[r] : o3[r];
            out[rowoff + d] = ov * inv[r] + x[rowoff + d];
        }
    }
}

// ---------------------------------------------------------------------------
// Fallback (round-3 kernel) if ws_size is too small for the prepass buffers
// ---------------------------------------------------------------------------
#define FKSS 264
#define FVTG 328
#define FPSS 40

__global__ __launch_bounds__(256, 2)
void fa_fallback(const float* __restrict__ x, const float* __restrict__ y,
                 const float* __restrict__ mask, float* __restrict__ out)
{
    __shared__ __align__(16) u16 Ks[32 * FKSS];
    __shared__ __align__(16) u32 Vt[16 * FVTG];
    __shared__ __align__(16) u16 Ps[64 * FPSS];

    const int tid  = threadIdx.x;
    const int wv   = tid >> 6;
    const int lane = tid & 63;
    const int l16  = lane & 15;
    const int quad = lane >> 4;
    const int b  = blockIdx.x >> 5;
    const int q0 = (blockIdx.x & 31) * 64;

    bf16x8 qfrag[8];
    {
        const float* xq = x + ((size_t)(b * SQL + q0 + wv * 16 + l16)) * DHD + quad * 8;
        #pragma unroll
        for (int s = 0; s < 8; ++s) {
            const float4 a = *(const float4*)(xq + s * 32);
            const float4 c = *(const float4*)(xq + s * 32 + 4);
            union { u32 w[4]; bf16x8 v; } u;
            u.w[0] = (u32)f2b(a.x) | ((u32)f2b(a.y) << 16);
            u.w[1] = (u32)f2b(a.z) | ((u32)f2b(a.w) << 16);
            u.w[2] = (u32)f2b(c.x) | ((u32)f2b(c.y) << 16);
            u.w[3] = (u32)f2b(c.z) | ((u32)f2b(c.w) << 16);
            qfrag[s] = u.v;
        }
    }
    f32x4 o[16] = {};
    float ls[4] = {0.f, 0.f, 0.f, 0.f};
    const int kv2 = tid & 15;
    const int dc  = tid >> 4;
    const float* ybase = y + ((size_t)b * SKVL) * DHD;
    float4 r0[4], r1[4];
    {
        const float* p0 = ybase + (size_t)(2 * kv2) * DHD + dc * 16;
        const float* p1 = p0 + DHD;
        #pragma unroll
        for (int p = 0; p < 4; ++p) { r0[p] = *(const float4*)(p0 + p * 4);
                                      r1[p] = *(const float4*)(p1 + p * 4); }
    }
    const float* mbase = mask + ((size_t)(b * SQL + q0 + wv * 16 + quad * 4)) * SKVL;
    float mkc0[4], mkc1[4], mkn0[4], mkn1[4];
    #pragma unroll
    for (int r = 0; r < 4; ++r) {
        const float* mp = mbase + (size_t)r * SKVL;
        mkc0[r] = mp[l16]; mkc1[r] = mp[16 + l16];
    }
    for (int it = 0; it < 64; ++it) {
        const int kv0 = it * 32;
        __syncthreads();
        {
            u16 e0[16], e1[16];
            #pragma unroll
            for (int p = 0; p < 4; ++p) {
                e0[p*4+0]=f2b(r0[p].x); e0[p*4+1]=f2b(r0[p].y);
                e0[p*4+2]=f2b(r0[p].z); e0[p*4+3]=f2b(r0[p].w);
                e1[p*4+0]=f2b(r1[p].x); e1[p*4+1]=f2b(r1[p].y);
                e1[p*4+2]=f2b(r1[p].z); e1[p*4+3]=f2b(r1[p].w);
            }
            union { u32 w[4]; uint4 q; } k0a, k0b, k1a, k1b;
            #pragma unroll
            for (int i = 0; i < 4; ++i) {
                k0a.w[i] = (u32)e0[2*i]   | ((u32)e0[2*i+1]   << 16);
                k0b.w[i] = (u32)e0[8+2*i] | ((u32)e0[8+2*i+1] << 16);
                k1a.w[i] = (u32)e1[2*i]   | ((u32)e1[2*i+1]   << 16);
                k1b.w[i] = (u32)e1[8+2*i] | ((u32)e1[8+2*i+1] << 16);
            }
            *(uint4*)(&Ks[(2*kv2)  *FKSS + dc*16])     = k0a.q;
            *(uint4*)(&Ks[(2*kv2)  *FKSS + dc*16 + 8]) = k0b.q;
            *(uint4*)(&Ks[(2*kv2+1)*FKSS + dc*16])     = k1a.q;
            *(uint4*)(&Ks[(2*kv2+1)*FKSS + dc*16 + 8]) = k1b.q;
            #pragma unroll
            for (int e = 0; e < 16; ++e)
                Vt[dc*FVTG + e*20 + kv2] = (u32)e0[e] | ((u32)e1[e] << 16);
        }
        __syncthreads();
        if (it + 1 < 64) {
            const float* p0 = ybase + (size_t)(kv0 + 32 + 2 * kv2) * DHD + dc * 16;
            const float* p1 = p0 + DHD;
            #pragma unroll
            for (int p = 0; p < 4; ++p) { r0[p] = *(const float4*)(p0 + p * 4);
                                          r1[p] = *(const float4*)(p1 + p * 4); }
        }
        {
            const int kvn2 = (it + 1 < 64) ? (kv0 + 32) : 0;
            #pragma unroll
            for (int r = 0; r < 4; ++r) {
                const float* mp = mbase + (size_t)r * SKVL + kvn2;
                mkn0[r] = mp[l16]; mkn1[r] = mp[16 + l16];
            }
        }
        f32x4 acc0 = {}, acc1 = {};
        #pragma unroll
        for (int s = 0; s < 8; ++s) {
            bf16x8 b0 = *(const bf16x8*)(&Ks[ l16     * FKSS + s*32 + quad*8]);
            bf16x8 b1 = *(const bf16x8*)(&Ks[(16+l16) * FKSS + s*32 + quad*8]);
            acc0 = __builtin_amdgcn_mfma_f32_16x16x32_bf16(qfrag[s], b0, acc0, 0, 0, 0);
            acc1 = __builtin_amdgcn_mfma_f32_16x16x32_bf16(qfrag[s], b1, acc1, 0, 0, 0);
        }
        #pragma unroll
        for (int r = 0; r < 4; ++r) {
            float p0 = __expf(acc0[r] * mkc0[r] * SCALE);
            float p1 = __expf(acc1[r] * mkc1[r] * SCALE);
            ls[r] += p0 + p1;
            u16* pr = &Ps[(wv*16 + quad*4 + r) * FPSS];
            pr[l16]      = f2b(p0);
            pr[16 + l16] = f2b(p1);
        }
        bf16x8 afrag = *(const bf16x8*)(&Ps[(wv*16 + l16) * FPSS + quad*8]);
        #pragma unroll
        for (int t = 0; t < 16; ++t) {
            bf16x8 bfrag = *(const bf16x8*)(&Vt[t*FVTG + l16*20 + quad*4]);
            o[t] = __builtin_amdgcn_mfma_f32_16x16x32_bf16(afrag, bfrag, o[t], 0, 0, 0);
        }
        #pragma unroll
        for (int r = 0; r < 4; ++r) { mkc0[r] = mkn0[r]; mkc1[r] = mkn1[r]; }
    }
    #pragma unroll
    for (int r = 0; r < 4; ++r) {
        float v = ls[r];
        v += __shfl_xor(v, 1); v += __shfl_xor(v, 2);
        v += __shfl_xor(v, 4); v += __shfl_xor(v, 8);
        ls[r] = 1.0f / v;
    }
    const int qrow = q0 + wv * 16 + quad * 4;
    #pragma unroll
    for (int r = 0; r < 4; ++r) {
        const size_t rowoff = ((size_t)(b * SQL + qrow + r)) * DHD;
        #pragma unroll
        for (int t = 0; t < 16; ++t) {
            const int d = t * 16 + l16;
            out[rowoff + d] = o[t][r] * ls[r] + x[rowoff + d];
        }
    }
}

extern "C" void kernel_launch(void* const* d_in, const int* in_sizes, int n_in,
                              void* d_out, int out_size, void* d_ws, size_t ws_size,
                              hipStream_t stream) {
    const float* x    = (const float*)d_in[0];
    const float* y    = (const float*)d_in[1];
    const float* mask = (const float*)d_in[2];
    float* out        = (float*)d_out;

    if (ws_size >= 33554432ull) {
        prepass<<<1024, 256, 0, stream>>>(y, (u16*)d_ws);
        fa_main<<<512, 256, 0, stream>>>(x, mask, (const u16*)d_ws, out);
    } else {
        fa_fallback<<<512, 256, 0, stream>>>(x, y, mask, out);
    }
}